// Round 9
// baseline (144.740 us; speedup 1.0000x reference)
//
#include <hip/hip_runtime.h>
#include <hip/hip_bf16.h>

// Problem: B=32, S=512, P=512, D=768
//   M = B*S = 16384 tokens, N = P = 512 prototypes, K = D = 768
// out[0 .. M*N)            = distances  ||x_m - p_n||^2  (fp32)
// out[M*N .. M*N + N*K)    = prototypes (fp32 passthrough)
//
// R9: B-in-LDS + L2-blocked A streaming.
//   prep  (R1-proven): fp32 -> bf16 ws copies + exact fp32 norms + proto out.
//   gemm: grid 512 = (nsl 0..15) x (mt 0..31); bid = nsl*32 + mt so
//         XCD(bid%8) = mt%8 -> each XCD touches 4 A-tiles (3 MB) + B (0.75 MB)
//         = 3.75 MB, fits its 4 MB L2. A's 16x re-read becomes L2 traffic.
//         512 thr / 8 waves; block tile 512 M x 32 N; wave tile 64 x 32.
//         B slice (32 x 768 bf16) staged ONCE into padded LDS [kc][row][40]
//         (60 KB -> 2 blocks/CU), ONE barrier, then barrier-free K-loop:
//         B frags via ds_read_b128 (latency-hideable), A frags global->VGPR
//         depth-1 prefetch. Epilogue rows = 32 floats = one full 128B line.

#define M_TOK 16384
#define N_PROT 512
#define K_DIM 768
#define BK 32
#define NCH (K_DIM / BK)   // 24
#define BSTR 40            // LDS B row stride in ushorts (80 B = 20 banks)

typedef __attribute__((ext_vector_type(4))) float f32x4;
typedef __attribute__((ext_vector_type(8))) short bf16x8;

__device__ inline unsigned short f2bf(float f) {
    // round-to-nearest-even on the bit pattern (finite inputs)
    unsigned int u = __float_as_uint(f);
    u += 0x7fffu + ((u >> 16) & 1u);
    return (unsigned short)(u >> 16);
}

// One wave per 768-float row. Rows [0, M_TOK) = tokens -> a_bf + x_sq.
// Rows [M_TOK, 16896) = prototypes -> b_bf + p_sq + fp32 passthrough.
__global__ __launch_bounds__(256) void prep_kernel(
    const float* __restrict__ x, const float* __restrict__ p,
    unsigned short* __restrict__ a_bf, unsigned short* __restrict__ b_bf,
    float* __restrict__ x_sq, float* __restrict__ p_sq,
    float* __restrict__ proto_out)
{
    const int row  = blockIdx.x * 4 + (threadIdx.x >> 6);
    const int lane = threadIdx.x & 63;

    const float4* src4;
    unsigned short* dst;
    float4* pout4 = nullptr;
    if (row < M_TOK) {
        src4 = (const float4*)(x + (size_t)row * K_DIM);
        dst  = a_bf + (size_t)row * K_DIM;
    } else {
        const int r = row - M_TOK;
        src4  = (const float4*)(p + (size_t)r * K_DIM);
        dst   = b_bf + (size_t)r * K_DIM;
        pout4 = (float4*)(proto_out + (size_t)r * K_DIM);
    }

    float ssum = 0.0f;
#pragma unroll
    for (int j = 0; j < 3; ++j) {        // 192 float4 per row / 64 lanes
        const int idx = lane + j * 64;
        float4 v = src4[idx];
        ssum += v.x * v.x + v.y * v.y + v.z * v.z + v.w * v.w;
        ushort4 b;
        b.x = f2bf(v.x); b.y = f2bf(v.y); b.z = f2bf(v.z); b.w = f2bf(v.w);
        ((ushort4*)dst)[idx] = b;
        if (pout4) pout4[idx] = v;
    }

#pragma unroll
    for (int off = 32; off > 0; off >>= 1) ssum += __shfl_down(ssum, off);
    if (lane == 0) {
        if (row < M_TOK) x_sq[row] = ssum;
        else             p_sq[row - M_TOK] = ssum;
    }
}

__global__ __launch_bounds__(512, 4) void gemm_kernel(
    const unsigned short* __restrict__ A,   // [M,K] bf16 (ws)
    const unsigned short* __restrict__ Bb,  // [N,K] bf16 (ws)
    const float* __restrict__ x_sq, const float* __restrict__ p_sq,
    float* __restrict__ out)                // [M,N] fp32
{
    __shared__ unsigned short lds_b[NCH * 32 * BSTR];   // 61,440 B
    __shared__ float unused_pad;                        // keep LDS < 64K class

    const int tid  = threadIdx.x;
    const int wave = tid >> 6;            // 0..7
    const int lane = tid & 63;
    const int bid  = blockIdx.x;
    const int mt_  = bid & 31;            // 0..31 -> XCD = mt_ % 8
    const int nsl  = bid >> 5;            // 0..15
    const int bm   = mt_ << 9;            // 512-row A tile
    const int bn   = nsl << 5;            // 32-col B slice
    const int quad = lane >> 4;           // 0..3
    const int l16  = lane & 15;

    // ---- one-time B staging: 32 rows x 768 bf16 -> LDS [kc][row][BSTR] ----
    {
        const int r  = tid >> 4;          // 0..31 row
        const int ci = tid & 15;          // chunk base
#pragma unroll
        for (int j = 0; j < 6; ++j) {
            const int c  = ci + 16 * j;   // 0..95 (96 x 16B chunks per row)
            const int kc = c >> 2;
            const int sb = c & 3;
            bf16x8 v = *(const bf16x8*)
                (Bb + (size_t)(bn + r) * K_DIM + kc * BK + sb * 8);
            *(bf16x8*)&lds_b[kc * (32 * BSTR) + r * BSTR + sb * 8] = v;
        }
    }
    __syncthreads();   // the ONLY barrier

    // ---- barrier-free K-loop: wave tile 64 M x 32 N ----
    const f32x4 zero = {0.0f, 0.0f, 0.0f, 0.0f};
    f32x4 acc[4][2];
#pragma unroll
    for (int mt = 0; mt < 4; ++mt)
#pragma unroll
        for (int nt = 0; nt < 2; ++nt) acc[mt][nt] = zero;

    // per-lane A fragment base: row (bm + wave*64 + mt*16 + l16), chunk quad*8
    const unsigned short* ap =
        A + (size_t)(bm + wave * 64 + l16) * K_DIM + quad * 8;

    bf16x8 acur[4], anxt[4];
#pragma unroll
    for (int mt = 0; mt < 4; ++mt)
        acur[mt] = *(const bf16x8*)(ap + (size_t)(mt * 16) * K_DIM);

    for (int kc = 0; kc < NCH; ++kc) {
        if (kc + 1 < NCH) {
#pragma unroll
            for (int mt = 0; mt < 4; ++mt)
                anxt[mt] = *(const bf16x8*)
                    (ap + (size_t)(mt * 16) * K_DIM + (kc + 1) * BK);
        }

        bf16x8 bfr[2];
#pragma unroll
        for (int nt = 0; nt < 2; ++nt)
            bfr[nt] = *(const bf16x8*)
                &lds_b[kc * (32 * BSTR) + (nt * 16 + l16) * BSTR + quad * 8];

#pragma unroll
        for (int mt = 0; mt < 4; ++mt)
#pragma unroll
            for (int nt = 0; nt < 2; ++nt)
                acc[mt][nt] = __builtin_amdgcn_mfma_f32_16x16x32_bf16(
                    acur[mt], bfr[nt], acc[mt][nt], 0, 0, 0);

#pragma unroll
        for (int mt = 0; mt < 4; ++mt) acur[mt] = anxt[mt];
    }

    // ---- epilogue: C/D layout col = lane&15, row = quad*4 + i ----
    float ps[2];
#pragma unroll
    for (int nt = 0; nt < 2; ++nt) ps[nt] = p_sq[bn + nt * 16 + l16];

#pragma unroll
    for (int mt = 0; mt < 4; ++mt) {
#pragma unroll
        for (int i = 0; i < 4; ++i) {
            const int gr = bm + wave * 64 + mt * 16 + quad * 4 + i;
            const float xs = x_sq[gr];
            float* orow = out + (size_t)gr * N_PROT + bn + l16;
            orow[0]  = xs + ps[0] - 2.0f * acc[mt][0][i];
            orow[16] = xs + ps[1] - 2.0f * acc[mt][1][i];
        }
    }
}

extern "C" void kernel_launch(void* const* d_in, const int* in_sizes, int n_in,
                              void* d_out, int out_size, void* d_ws, size_t ws_size,
                              hipStream_t stream) {
    const float* inputs = (const float*)d_in[0];   // [32,512,768] fp32
    const float* protos = (const float*)d_in[1];   // [512,768]    fp32
    float* out = (float*)d_out;

    // workspace layout (all 16B-aligned):
    //   a_bf : M*K bf16 = 25,165,824 B
    //   b_bf : N*K bf16 =    786,432 B
    //   x_sq : M fp32   =     65,536 B
    //   p_sq : N fp32   =      2,048 B
    char* ws = (char*)d_ws;
    unsigned short* a_bf = (unsigned short*)ws;
    unsigned short* b_bf = (unsigned short*)(ws + 25165824);
    float* x_sq = (float*)(ws + 25165824 + 786432);
    float* p_sq = (float*)(ws + 25165824 + 786432 + 65536);
    float* proto_out = out + (size_t)M_TOK * N_PROT;   // second tuple element

    // 16896 rows / 4 rows-per-block
    prep_kernel<<<4224, 256, 0, stream>>>(inputs, protos, a_bf, b_bf, x_sq, p_sq, proto_out);

    // 512 blocks: bid = nsl*32 + mt  (XCD = bid%8 = mt%8)
    gemm_kernel<<<512, 512, 0, stream>>>(a_bf, b_bf, x_sq, p_sq, out);
}